// Round 5
// baseline (1733.593 us; speedup 1.0000x reference)
//
#include <hip/hip_runtime.h>
#include <hip/hip_bf16.h>

typedef unsigned short u16;
typedef short s8v __attribute__((ext_vector_type(8)));   // 8 bf16 as i16 (4 VGPRs)
typedef float f4v __attribute__((ext_vector_type(4)));   // MFMA 16x16 accumulator

// ---------- helpers ----------
__device__ __forceinline__ float b2f(u16 u) { return __uint_as_float(((unsigned)u) << 16); }
__device__ __forceinline__ u16 f2b(float f) {
    unsigned u = __float_as_uint(f);
    unsigned r = 0x7FFFu + ((u >> 16) & 1u);
    return (u16)((u + r) >> 16);
}
__device__ __forceinline__ float silu_f(float x) { return x / (1.0f + expf(-x)); }

__device__ __forceinline__ void gld16(const u16* g, u16* l) {
    __builtin_amdgcn_global_load_lds((const __attribute__((address_space(1))) unsigned*)g,
                                     (__attribute__((address_space(3))) unsigned*)l, 16, 0, 0);
}

// shared MFMA inner block: BK=64 staged in Al/Bl (XOR-swizzled), 4x4 16x16 tiles/wave
__device__ __forceinline__ void mfma_block(const u16* Al, const u16* Bl, f4v acc[4][4],
                                           int wr, int wc, int l15, int quad, int l7) {
#pragma unroll
    for (int ks = 0; ks < 2; ++ks) {
        s8v af[4], bf[4];
        int cch = ((ks * 4 + quad) ^ l7) * 8;
#pragma unroll
        for (int mi = 0; mi < 4; ++mi)
            af[mi] = *(const s8v*)(Al + (wr * 64 + mi * 16 + l15) * 64 + cch);
#pragma unroll
        for (int ni = 0; ni < 4; ++ni)
            bf[ni] = *(const s8v*)(Bl + (wc * 64 + ni * 16 + l15) * 64 + cch);
#pragma unroll
        for (int mi = 0; mi < 4; ++mi)
#pragma unroll
            for (int ni = 0; ni < 4; ++ni)
                acc[mi][ni] = __builtin_amdgcn_mfma_f32_16x16x32_bf16(af[mi], bf[ni], acc[mi][ni], 0, 0, 0);
    }
}

// ================== 256x256 GEMM core (BK=32, double-buffered, 2 blocks/CU) =====================
// 512 threads = 8 waves (2M x 4N); per-wave output 128x64. LDS = 2 bufs x (A[256x32]+B[256x32])
// = 64 KB -> two independent blocks co-resident per CU; one block's compute covers the other's
// vmcnt/barrier stalls. Per tile: STAGE(next) first, then 12 ds_read_b128 + 32 MFMA, then ONE
// vmcnt(0)+barrier (T3 "minimum 2-phase" recipe). Staging into buf (T+1)&1 is race-free: that
// buffer's reads finished before the end-of-tile(T-1) barrier.
// LDS swizzle: 32-u16 rows, chunk = k ^ (row&3) ^ ((row>>2)&3), same on write-source and read.

// stage one 256x32 plane (A or B) of a K-tile into LDS, block-cooperative, pre-swizzled source
__device__ __forceinline__ void stage_half(const u16* __restrict__ src, int K, int kbase,
                                           u16* dst, int t) {
    const int row = t >> 2, ch = t & 3;
    const int csw = (ch ^ (row & 3) ^ ((row >> 2) & 3)) * 8;   // (row+128) -> same swizzle
    gld16(src + (size_t)row * K + kbase + csw, dst + row * 32 + ch * 8);
    gld16(src + (size_t)(row + 128) * K + kbase + csw, dst + (row + 128) * 32 + ch * 8);
}

__device__ __forceinline__ void readA4(const u16* Ab, s8v af[4], int rbase, int l15, int quad) {
#pragma unroll
    for (int mi = 0; mi < 4; ++mi) {
        int ra = rbase + mi * 16 + l15;
        af[mi] = *(const s8v*)(Ab + ra * 32 + ((quad ^ (ra & 3) ^ ((ra >> 2) & 3)) * 8));
    }
}

__device__ __forceinline__ void kloop256(const u16* __restrict__ Ag, const u16* __restrict__ Bg,
                                         int K, int NT, u16* lds, f4v (&acc)[8][4],
                                         int t, int wm, int wn, int l15, int quad) {
    // prologue: stage tile 0
    stage_half(Ag, K, 0, lds, t);
    stage_half(Bg, K, 0, lds + 8192, t);
    asm volatile("s_waitcnt vmcnt(0)" ::: "memory");
    __builtin_amdgcn_s_barrier();

    for (int T = 0; T < NT; ++T) {
        const u16* Ab = lds + (T & 1) * 16384;
        const u16* Bb = Ab + 8192;
        u16* nxt = lds + ((T + 1) & 1) * 16384;
        // issue next-tile staging FIRST (hides HBM latency under this tile's compute)
        if (T + 1 < NT) {
            stage_half(Ag, K, (T + 1) * 32, nxt, t);
            stage_half(Bg, K, (T + 1) * 32, nxt + 8192, t);
        }
        // compute current tile: 4 B-frags (reused), 2x4 A-frags, 32 MFMA
        s8v bf[4];
#pragma unroll
        for (int ni = 0; ni < 4; ++ni) {
            int rb = wn * 64 + ni * 16 + l15;
            bf[ni] = *(const s8v*)(Bb + rb * 32 + ((quad ^ (rb & 3) ^ ((rb >> 2) & 3)) * 8));
        }
#pragma unroll
        for (int mg = 0; mg < 2; ++mg) {
            s8v af[4];
            readA4(Ab, af, wm * 128 + mg * 64, l15, quad);
            __builtin_amdgcn_s_setprio(1);
#pragma unroll
            for (int mi = 0; mi < 4; ++mi)
#pragma unroll
                for (int ni = 0; ni < 4; ++ni)
                    acc[mg * 4 + mi][ni] =
                        __builtin_amdgcn_mfma_f32_16x16x32_bf16(af[mi], bf[ni], acc[mg * 4 + mi][ni], 0, 0, 0);
            __builtin_amdgcn_s_setprio(0);
        }
        // ONE drain + barrier per tile; sibling block on the CU covers this stall
        asm volatile("s_waitcnt vmcnt(0)" ::: "memory");
        __builtin_amdgcn_s_barrier();
    }
}

// ---------- constants ----------
// DIM=1024, HID=2048, QK=128, G=256, NG=16, B=4, ROWS=16384
// I/O fp32; intermediates bf16. heads: 0=quad_q 1=lin_q 2=quad_k 3=lin_k

// ---------- fp32 -> bf16 transpose (weights) ----------
__global__ __launch_bounds__(256) void convT_kernel(const float* __restrict__ in,
                                                    u16* __restrict__ out, int K, int N) {
    __shared__ float tile[32][33];
    int k0 = blockIdx.y * 32, n0 = blockIdx.x * 32;
    int t = threadIdx.x;
    int r = t >> 5, c = t & 31;
#pragma unroll
    for (int rr = r; rr < 32; rr += 8) tile[rr][c] = in[(size_t)(k0 + rr) * N + n0 + c];
    __syncthreads();
#pragma unroll
    for (int rr = r; rr < 32; rr += 8) out[(size_t)(n0 + rr) * K + k0 + c] = f2b(tile[c][rr]);
}

// ---------- LayerNorm: fp32 in -> bf16 out ----------
__global__ __launch_bounds__(256) void ln_kernel(const float* __restrict__ x,
                                                 const float* __restrict__ w,
                                                 const float* __restrict__ bsh,
                                                 u16* __restrict__ out) {
    int row = blockIdx.x, t = threadIdx.x;
    const float* xr = x + (size_t)row * 1024;
    float4 u = *reinterpret_cast<const float4*>(xr + t * 4);
    float s = u.x + u.y + u.z + u.w;
    float s2 = u.x * u.x + u.y * u.y + u.z * u.z + u.w * u.w;
#pragma unroll
    for (int o = 32; o; o >>= 1) {
        s += __shfl_down(s, o, 64);
        s2 += __shfl_down(s2, o, 64);
    }
    __shared__ float rs[4], rs2[4];
    int wid = t >> 6;
    if ((t & 63) == 0) { rs[wid] = s; rs2[wid] = s2; }
    __syncthreads();
    float S = rs[0] + rs[1] + rs[2] + rs[3];
    float S2 = rs2[0] + rs2[1] + rs2[2] + rs2[3];
    float mu = S * (1.0f / 1024.0f);
    float var = S2 * (1.0f / 1024.0f) - mu * mu;
    float rinv = rsqrtf(var + 1e-5f);
    float4 uw = *reinterpret_cast<const float4*>(w + t * 4);
    float4 ub = *reinterpret_cast<const float4*>(bsh + t * 4);
    ushort4 o;
    o.x = f2b((u.x - mu) * rinv * uw.x + ub.x);
    o.y = f2b((u.y - mu) * rinv * uw.y + ub.y);
    o.z = f2b((u.z - mu) * rinv * uw.z + ub.z);
    o.w = f2b((u.w - mu) * rinv * uw.w + ub.w);
    *reinterpret_cast<ushort4*>(out + (size_t)row * 1024 + t * 4) = o;
}

// ---------- Wh GEMM (256^2 dbuf, 2 blk/CU): silu(normed @ WhT^T + bh) -> vT | gate ----------
__global__ __launch_bounds__(512, 4) void gemm_hv256(const u16* __restrict__ A,
                                                     const u16* __restrict__ Bt,
                                                     const float* __restrict__ bias,
                                                     u16* __restrict__ vT,
                                                     u16* __restrict__ gate) {
    __shared__ __align__(16) u16 lds8[32768];   // 64 KB -> 2 blocks/CU
    const int t = threadIdx.x;
    const int lane = t & 63, w = t >> 6;
    const int wm = w >> 2, wn = w & 3;
    const int l15 = lane & 15, quad = lane >> 4;

    int wg = blockIdx.x;                 // nwg = 1024, XCD-bijective swizzle (1024%8==0)
    wg = (wg & 7) * 128 + (wg >> 3);
    const int by = wg >> 4, bx = wg & 15;
    const int m0 = by * 256, n0 = bx * 256;

    f4v acc[8][4] = {};
    kloop256(A + (size_t)m0 * 1024, Bt + (size_t)n0 * 1024, 1024, 32,
             lds8, acc, t, wm, wn, l15, quad);

    const bool isV = (n0 < 2048);
    const int bg = by;                   // 256-row tiles align with groups
#pragma unroll
    for (int ni = 0; ni < 4; ++ni) {
        int n = n0 + wn * 64 + ni * 16 + l15;
        float bs = bias[n];
#pragma unroll
        for (int mi = 0; mi < 8; ++mi) {
            int mloc = wm * 128 + mi * 16 + quad * 4;
            if (isV) {
                ushort4 o;
                o.x = f2b(silu_f(acc[mi][ni][0] + bs));
                o.y = f2b(silu_f(acc[mi][ni][1] + bs));
                o.z = f2b(silu_f(acc[mi][ni][2] + bs));
                o.w = f2b(silu_f(acc[mi][ni][3] + bs));
                *reinterpret_cast<ushort4*>(vT + ((size_t)bg * 2048 + n) * 256 + mloc) = o;
            } else {
#pragma unroll
                for (int reg = 0; reg < 4; ++reg)
                    gate[(size_t)(m0 + mloc + reg) * 2048 + (n - 2048)] =
                        f2b(silu_f(acc[mi][ni][reg] + bs));
            }
        }
    }
}

// ---------- final GEMM (256^2 dbuf, 2 blk/CU): gated @ WoutT^T + bout + x -> fp32 out ----------
__global__ __launch_bounds__(512, 4) void gemm_out256(const u16* __restrict__ A,
                                                      const u16* __restrict__ Bt,
                                                      const float* __restrict__ bias,
                                                      const float* __restrict__ resid,
                                                      float* __restrict__ C) {
    __shared__ __align__(16) u16 lds8[32768];
    const int t = threadIdx.x;
    const int lane = t & 63, w = t >> 6;
    const int wm = w >> 2, wn = w & 3;
    const int l15 = lane & 15, quad = lane >> 4;

    int wg = blockIdx.x;                 // nwg = 256, swizzle (256%8==0)
    wg = (wg & 7) * 32 + (wg >> 3);
    const int by = wg >> 2, bx = wg & 3;
    const int m0 = by * 256, n0 = bx * 256;

    f4v acc[8][4] = {};
    kloop256(A + (size_t)m0 * 2048, Bt + (size_t)n0 * 2048, 2048, 64,
             lds8, acc, t, wm, wn, l15, quad);

#pragma unroll
    for (int ni = 0; ni < 4; ++ni) {
        int n = n0 + wn * 64 + ni * 16 + l15;
        float bs = bias[n];
#pragma unroll
        for (int mi = 0; mi < 8; ++mi) {
#pragma unroll
            for (int reg = 0; reg < 4; ++reg) {
                int m = m0 + wm * 128 + mi * 16 + quad * 4 + reg;
                C[(size_t)m * 1024 + n] = acc[mi][ni][reg] + bs + resid[(size_t)m * 1024 + n];
            }
        }
    }
}

// ---------- qk projection MFMA GEMM: silu(normed @ WqkT^T + bqk) -> qk [16384][128] ----------
__global__ __launch_bounds__(256) void gemm_qk(const u16* __restrict__ A,
                                               const u16* __restrict__ Bt,
                                               const float* __restrict__ bias,
                                               u16* __restrict__ C) {
    __shared__ __align__(16) u16 Al[128 * 64];
    __shared__ __align__(16) u16 Bl[128 * 64];
    const int t = threadIdx.x;
    const int lane = t & 63, w = t >> 6;
    const int wr = w >> 1, wc = w & 1;
    const int l15 = lane & 15, quad = lane >> 4, l7 = lane & 7;
    const int m0 = blockIdx.y * 128;    // N fixed at 128 -> n0 = 0
    const int sr = t >> 3, ss = t & 7;

    f4v acc[4][4] = {};
    for (int k0 = 0; k0 < 1024; k0 += 64) {
#pragma unroll
        for (int i = 0; i < 4; ++i) {
            int r = i * 32 + sr;
            int q = ss ^ (r & 7);
            gld16(A + (size_t)(m0 + r) * 1024 + q * 8 + k0, Al + i * 2048 + t * 8);
            gld16(Bt + (size_t)r * 1024 + q * 8 + k0, Bl + i * 2048 + t * 8);
        }
        __syncthreads();
        mfma_block(Al, Bl, acc, wr, wc, l15, quad, l7);
        __syncthreads();
    }
#pragma unroll
    for (int ni = 0; ni < 4; ++ni) {
        int n = wc * 64 + ni * 16 + l15;
        float bs = bias[n];
#pragma unroll
        for (int mi = 0; mi < 4; ++mi) {
#pragma unroll
            for (int reg = 0; reg < 4; ++reg) {
                int m = m0 + wr * 64 + mi * 16 + quad * 4 + reg;
                C[(size_t)m * 128 + n] = f2b(silu_f(acc[mi][ni][reg] + bs));
            }
        }
    }
}

// ---------- lin_k transpose+scale: klT[bg][d][j] = b2f(qk[bg*256+j][d]) * w3[d] + b3[d] ----------
__global__ __launch_bounds__(256) void klT_kernel(const u16* __restrict__ qk,
                                                  const float* __restrict__ qk_w,
                                                  const float* __restrict__ qk_b,
                                                  u16* __restrict__ klT) {
    __shared__ __align__(16) u16 tile[64][128];
    const int bg = blockIdx.x >> 2, jc = (blockIdx.x & 3) * 64;
    const int t = threadIdx.x;
    const int r = t >> 4, c = (t & 15) * 8;
#pragma unroll
    for (int rr = 0; rr < 64; rr += 16)
        *(s8v*)(&tile[r + rr][c]) =
            *(const s8v*)(qk + (size_t)(bg * 256 + jc + r + rr) * 128 + c);
    __syncthreads();
    const int d = t & 127, jb = (t >> 7) * 32;
    const float kw = qk_w[3 * 128 + d], kb = qk_b[3 * 128 + d];
    s8v ov[4];
#pragma unroll
    for (int q = 0; q < 4; ++q)
#pragma unroll
        for (int j = 0; j < 8; ++j)
            ov[q][j] = (short)f2b(b2f(tile[jb + q * 8 + j][d]) * kw + kb);
    u16* dst = klT + ((size_t)bg * 128 + d) * 256 + jc + jb;
#pragma unroll
    for (int q = 0; q < 4; ++q) *(s8v*)(dst + q * 8) = ov[q];
}

// ---------- scores: Sbuf[bg][i][0..255] = relu^2(qq.kk^T/256 + t5bias, causal), [256..383] = lq ----------
__global__ __launch_bounds__(256) void scores_kernel(const u16* __restrict__ qk,
                                                     const float* __restrict__ qk_w,
                                                     const float* __restrict__ qk_b,
                                                     const float* __restrict__ rel_table,
                                                     u16* __restrict__ Sbuf) {
    __shared__ __align__(16) u16 qkl[256 * 128];   // raw qk rows for this group (64KB)
    __shared__ float biasn[256];
    __shared__ float w0[128], b0[128], w1[128], b1[128], w2[128], b2v[128];
    const int t = threadIdx.x;
    const int bg = blockIdx.x >> 1, mt = blockIdx.x & 1;
    const int lane = t & 63, w = t >> 6;
    const int wr = w >> 1, wc = w & 1;
    const int l15 = lane & 15, quad = lane >> 4;

    if (t < 128) {
        w0[t] = qk_w[t];        b0[t] = qk_b[t];
        w1[t] = qk_w[128 + t];  b1[t] = qk_b[128 + t];
        w2[t] = qk_w[256 + t];  b2v[t] = qk_b[256 + t];
    }
    {
        int n = t;
        int bucket;
        if (n < 16) bucket = n;
        else {
            float v = logf((float)n / 16.0f) / 2.0794415416798357f * 16.0f;
            int vl = 16 + (int)v;
            bucket = vl > 31 ? 31 : vl;
        }
        biasn[n] = rel_table[bucket] * 11.313708498984761f;
    }
    // stage all 256 rows x 128 cols of this group's qk
#pragma unroll
    for (int it = 0; it < 16; ++it) {
        int r = (t >> 4) + it * 16, c = (t & 15) * 8;
        *(s8v*)(qkl + r * 128 + c) = *(const s8v*)(qk + ((size_t)(bg * 256 + r)) * 128 + c);
    }
    __syncthreads();

    // wave tile: 64 m-rows x 128 n-cols; block: 128 rows (mt) x 256 cols
    f4v acc[4][8] = {};
#pragma unroll
    for (int kstep = 0; kstep < 4; ++kstep) {
        int kc = kstep * 32 + quad * 8;
        float w0f[8], b0f[8], w2f[8], b2f_[8];
#pragma unroll
        for (int j = 0; j < 8; ++j) {
            w0f[j] = w0[kc + j]; b0f[j] = b0[kc + j];
            w2f[j] = w2[kc + j]; b2f_[j] = b2v[kc + j];
        }
        s8v af[4];
#pragma unroll
        for (int mi = 0; mi < 4; ++mi) {
            int ra = mt * 128 + wr * 64 + mi * 16 + l15;
            s8v raw = *(const s8v*)(qkl + ra * 128 + kc);
#pragma unroll
            for (int j = 0; j < 8; ++j) af[mi][j] = (short)f2b(b2f((u16)raw[j]) * w0f[j] + b0f[j]);
        }
#pragma unroll
        for (int np = 0; np < 2; ++np) {
            s8v bf[4];
#pragma unroll
            for (int ni = 0; ni < 4; ++ni) {
                int rb = wc * 128 + (np * 4 + ni) * 16 + l15;
                s8v raw = *(const s8v*)(qkl + rb * 128 + kc);
#pragma unroll
                for (int j = 0; j < 8; ++j) bf[ni][j] = (short)f2b(b2f((u16)raw[j]) * w2f[j] + b2f_[j]);
            }
#pragma unroll
            for (int mi = 0; mi < 4; ++mi)
#pragma unroll
                for (int ni = 0; ni < 4; ++ni)
                    acc[mi][np * 4 + ni] = __builtin_amdgcn_mfma_f32_16x16x32_bf16(af[mi], bf[ni], acc[mi][np * 4 + ni], 0, 0, 0);
        }
    }
    // epilogue: bias + relu^2 + causal -> bf16 Sbuf
#pragma unroll
    for (int ni = 0; ni < 8; ++ni) {
        int gj = wc * 128 + ni * 16 + l15;
#pragma unroll
        for (int mi = 0; mi < 4; ++mi) {
#pragma unroll
            for (int reg = 0; reg < 4; ++reg) {
                int gi = mt * 128 + wr * 64 + mi * 16 + quad * 4 + reg;
                float aval = 0.0f;
                if (gj <= gi) {
                    float sv = acc[mi][ni][reg] * (1.0f / 256.0f) + biasn[gi - gj];
                    sv = fmaxf(sv, 0.0f);
                    aval = sv * sv;
                }
                Sbuf[((size_t)bg * 256 + gi) * 384 + gj] = f2b(aval);
            }
        }
    }
    // lq columns 256..383
#pragma unroll
    for (int it = 0; it < 8; ++it) {
        int i = mt * 128 + (t >> 4) + it * 16;
        int d = (t & 15) * 8;
        s8v raw = *(const s8v*)(qkl + i * 128 + d);
        u16* dst = Sbuf + ((size_t)bg * 256 + i) * 384 + 256 + d;
#pragma unroll
        for (int j = 0; j < 8; ++j)
            dst[j] = f2b(b2f((u16)raw[j]) * w1[d + j] + b1[d + j]);
    }
}

// ---------- per-group kv MFMA GEMM: kvT[e][d] = (1/256) * sum_j vT[e][j] * klT[d][j] ----------
__global__ __launch_bounds__(256) void kv_gemm(const u16* __restrict__ vT,
                                               const u16* __restrict__ klT,
                                               u16* __restrict__ kvT) {
    __shared__ __align__(16) u16 Al[128 * 64];
    __shared__ __align__(16) u16 Bl[128 * 64];
    const int t = threadIdx.x;
    const int lane = t & 63, w = t >> 6;
    const int wr = w >> 1, wc = w & 1;
    const int l15 = lane & 15, quad = lane >> 4, l7 = lane & 7;
    const int bg = blockIdx.y, m0 = blockIdx.x * 128;   // m = e, n = d (128 total)
    const int sr = t >> 3, ss = t & 7;

    const u16* Av = vT + (size_t)bg * 2048 * 256;
    const u16* Bk = klT + (size_t)bg * 128 * 256;

    f4v acc[4][4] = {};
    for (int k0 = 0; k0 < 256; k0 += 64) {
#pragma unroll
        for (int i = 0; i < 4; ++i) {
            int r = i * 32 + sr;
            int q = ss ^ (r & 7);
            gld16(Av + (size_t)(m0 + r) * 256 + q * 8 + k0, Al + i * 2048 + t * 8);
            gld16(Bk + (size_t)r * 256 + q * 8 + k0, Bl + i * 2048 + t * 8);
        }
        __syncthreads();
        mfma_block(Al, Bl, acc, wr, wc, l15, quad, l7);
        __syncthreads();
    }
#pragma unroll
    for (int ni = 0; ni < 4; ++ni) {
        int n = wc * 64 + ni * 16 + l15;
#pragma unroll
        for (int mi = 0; mi < 4; ++mi) {
#pragma unroll
            for (int reg = 0; reg < 4; ++reg) {
                int m = m0 + wr * 64 + mi * 16 + quad * 4 + reg;
                kvT[((size_t)bg * 2048 + m) * 128 + n] = f2b(acc[mi][ni][reg] * (1.0f / 256.0f));
            }
        }
    }
}

// ---------- shifted cumsum over groups (in-place, kvT layout [b][g][e][d]) ----------
__global__ __launch_bounds__(256) void prefix_kernel(u16* __restrict__ kvT) {
    size_t tid = (size_t)blockIdx.x * 256 + threadIdx.x;  // 1,048,576
    int d = (int)(tid & 127);
    int e = (int)((tid >> 7) & 2047);
    int b = (int)(tid >> 18);
    size_t base = ((size_t)(b * 16) * 2048 + e) * 128 + d;
    const size_t gs = 2048 * 128;
    float vals[16];
#pragma unroll
    for (int g = 0; g < 16; ++g) vals[g] = b2f(kvT[base + (size_t)g * gs]);
    float s = 0.0f;
#pragma unroll
    for (int g = 0; g < 16; ++g) {
        kvT[base + (size_t)g * gs] = f2b(s);
        s += vals[g];
    }
}

// ---------- attention GEMM: out = [S|lq] @ [v;kv], times gate, in place over gate ----------
__global__ __launch_bounds__(256) void attn_gemm(const u16* __restrict__ Sbuf,
                                                 const u16* __restrict__ vT,
                                                 const u16* __restrict__ kvT,
                                                 u16* __restrict__ gate) {
    __shared__ __align__(16) u16 Al[128 * 64];
    __shared__ __align__(16) u16 Bl[128 * 64];
    const int t = threadIdx.x;
    const int lane = t & 63, w = t >> 6;
    const int wr = w >> 1, wc = w & 1;
    const int l15 = lane & 15, quad = lane >> 4, l7 = lane & 7;
    const int bg = blockIdx.y >> 1, mt = blockIdx.y & 1;
    const int n0 = blockIdx.x * 128;   // e offset
    const int sr = t >> 3, ss = t & 7;

    const u16* Abase = Sbuf + ((size_t)bg * 256 + mt * 128) * 384;
    const u16* Bv = vT + (size_t)bg * 2048 * 256;
    const u16* Bk = kvT + (size_t)bg * 2048 * 128;

    f4v acc[4][4] = {};
    // phase 1: K=256 (S @ v)
    for (int k0 = 0; k0 < 256; k0 += 64) {
#pragma unroll
        for (int i = 0; i < 4; ++i) {
            int r = i * 32 + sr;
            int q = ss ^ (r & 7);
            gld16(Abase + (size_t)r * 384 + q * 8 + k0, Al + i * 2048 + t * 8);
            gld16(Bv + (size_t)(n0 + r) * 256 + q * 8 + k0, Bl + i * 2048 + t * 8);
        }
        __syncthreads();
        mfma_block(Al, Bl, acc, wr, wc, l15, quad, l7);
        __syncthreads();
    }
    // phase 2: K=128 (lq @ kv_pref)
    for (int k0 = 0; k0 < 128; k0 += 64) {
#pragma unroll
        for (int i = 0; i < 4; ++i) {
            int r = i * 32 + sr;
            int q = ss ^ (r & 7);
            gld16(Abase + (size_t)r * 384 + 256 + q * 8 + k0, Al + i * 2048 + t * 8);
            gld16(Bk + (size_t)(n0 + r) * 128 + q * 8 + k0, Bl + i * 2048 + t * 8);
        }
        __syncthreads();
        mfma_block(Al, Bl, acc, wr, wc, l15, quad, l7);
        __syncthreads();
    }
    // epilogue: multiply by gate, write gated in place
#pragma unroll
    for (int ni = 0; ni < 4; ++ni) {
        int e = n0 + wc * 64 + ni * 16 + l15;
#pragma unroll
        for (int mi = 0; mi < 4; ++mi) {
#pragma unroll
            for (int reg = 0; reg < 4; ++reg) {
                int gi = mt * 128 + wr * 64 + mi * 16 + quad * 4 + reg;
                u16* p = gate + ((size_t)bg * 256 + gi) * 2048 + e;
                *p = f2b(acc[mi][ni][reg] * b2f(*p));
            }
        }
    }
}

// ---------- launch ----------
extern "C" void kernel_launch(void* const* d_in, const int* in_sizes, int n_in,
                              void* d_out, int out_size, void* d_ws, size_t ws_size,
                              hipStream_t stream) {
    const float* x = (const float*)d_in[0];
    const float* ln_w = (const float*)d_in[1];
    const float* ln_b = (const float*)d_in[2];
    const float* Wh = (const float*)d_in[3];
    const float* bh = (const float*)d_in[4];
    const float* Wqk = (const float*)d_in[5];
    const float* bqk = (const float*)d_in[6];
    const float* qk_w = (const float*)d_in[7];
    const float* qk_b = (const float*)d_in[8];
    const float* rel_table = (const float*)d_in[9];
    const float* Wout = (const float*)d_in[10];
    const float* bout = (const float*)d_in[11];
    float* out = (float*)d_out;

    char* ws = (char*)d_ws;
    u16* normed = (u16*)(ws);                  // 32 MB (dead after projections)
    u16* kvT    = (u16*)(ws);                  // aliases normed: [64][2048][128] 32 MB
    u16* gate   = (u16*)(ws + 33554432ull);    // [16384][2048] 64 MB (gate -> gated)
    u16* vT     = (u16*)(ws + 100663296ull);   // [64][2048][256] 64 MB
    u16* qk     = (u16*)(ws + 167772160ull);   // [16384][128] 4 MB
    u16* WhT    = (u16*)(ws + 171966464ull);   // [4096][1024] 8 MB (dead after gemm_hv)
    u16* klT    = (u16*)(ws + 171966464ull);   // aliases WhT: [64][128][256] 4 MB
    u16* WoutT  = (u16*)(ws + 180355072ull);   // [1024][2048] 4 MB
    u16* Sbuf   = (u16*)(ws + 184549376ull);   // [64][256][384] 12,582,912 B
    u16* WqkT   = (u16*)(ws + 184549376ull);   // aliases Sbuf head: [128][1024] 256 KB (dead before scores)
    // total = 197,132,288 B (~188 MiB)

    convT_kernel<<<dim3(128, 32), 256, 0, stream>>>(Wh, WhT, 1024, 4096);
    convT_kernel<<<dim3(32, 64), 256, 0, stream>>>(Wout, WoutT, 2048, 1024);
    convT_kernel<<<dim3(4, 32), 256, 0, stream>>>(Wqk, WqkT, 1024, 128);
    ln_kernel<<<16384, 256, 0, stream>>>(x, ln_w, ln_b, normed);
    gemm_hv256<<<1024, 512, 0, stream>>>(normed, WhT, bh, vT, gate);
    gemm_qk<<<dim3(1, 128), 256, 0, stream>>>(normed, WqkT, bqk, qk);
    klT_kernel<<<256, 256, 0, stream>>>(qk, qk_w, qk_b, klT);
    scores_kernel<<<128, 256, 0, stream>>>(qk, qk_w, qk_b, rel_table, Sbuf);
    kv_gemm<<<dim3(16, 64), 256, 0, stream>>>(vT, klT, kvT);
    prefix_kernel<<<4096, 256, 0, stream>>>(kvT);
    attn_gemm<<<dim3(16, 128), 256, 0, stream>>>(Sbuf, vT, kvT, gate);
    gemm_out256<<<256, 512, 0, stream>>>(gate, WoutT, bout, x, out);
}

// Round 6
// 577.545 us; speedup vs baseline: 3.0017x; 3.0017x over previous
//
#include <hip/hip_runtime.h>
#include <hip/hip_bf16.h>

typedef unsigned short u16;
typedef short s8v __attribute__((ext_vector_type(8)));   // 8 bf16 as i16 (4 VGPRs)
typedef float f4v __attribute__((ext_vector_type(4)));   // MFMA 16x16 accumulator

// ---------- helpers ----------
__device__ __forceinline__ float b2f(u16 u) { return __uint_as_float(((unsigned)u) << 16); }
__device__ __forceinline__ u16 f2b(float f) {
    unsigned u = __float_as_uint(f);
    unsigned r = 0x7FFFu + ((u >> 16) & 1u);
    return (u16)((u + r) >> 16);
}
__device__ __forceinline__ float silu_f(float x) { return x / (1.0f + expf(-x)); }

__device__ __forceinline__ void gld16(const u16* g, u16* l) {
    __builtin_amdgcn_global_load_lds((const __attribute__((address_space(1))) unsigned*)g,
                                     (__attribute__((address_space(3))) unsigned*)l, 16, 0, 0);
}

// shared MFMA inner block: BK=64 staged in Al/Bl (XOR-swizzled), 4x4 16x16 tiles/wave
__device__ __forceinline__ void mfma_block(const u16* Al, const u16* Bl, f4v acc[4][4],
                                           int wr, int wc, int l15, int quad, int l7) {
#pragma unroll
    for (int ks = 0; ks < 2; ++ks) {
        s8v af[4], bf[4];
        int cch = ((ks * 4 + quad) ^ l7) * 8;
#pragma unroll
        for (int mi = 0; mi < 4; ++mi)
            af[mi] = *(const s8v*)(Al + (wr * 64 + mi * 16 + l15) * 64 + cch);
#pragma unroll
        for (int ni = 0; ni < 4; ++ni)
            bf[ni] = *(const s8v*)(Bl + (wc * 64 + ni * 16 + l15) * 64 + cch);
#pragma unroll
        for (int mi = 0; mi < 4; ++mi)
#pragma unroll
            for (int ni = 0; ni < 4; ++ni)
                acc[mi][ni] = __builtin_amdgcn_mfma_f32_16x16x32_bf16(af[mi], bf[ni], acc[mi][ni], 0, 0, 0);
    }
}

// ============ shared 256-wide staging (LDS plane [256][32] u16, XOR-swizzled) ============
// chunk swizzle: c ^ (row&3) ^ ((row>>2)&3) -> wave64 b128 reads hit the 2-lane/bank floor.
__device__ __forceinline__ void stage_plane(const u16* __restrict__ src, int K, int kbase,
                                            u16* dst, int t) {
    const int row = t >> 2, ch = t & 3;
    const int csw = (ch ^ (row & 3) ^ ((row >> 2) & 3)) * 8;   // (row+128) -> same swizzle
    gld16(src + (size_t)row * K + kbase + csw, dst + row * 32 + ch * 8);
    gld16(src + (size_t)(row + 128) * K + kbase + csw, dst + (row + 128) * 32 + ch * 8);
}

__device__ __forceinline__ void read_frag4(const u16* plane, s8v (&f)[4], int rbase, int l15, int quad) {
#pragma unroll
    for (int mi = 0; mi < 4; ++mi) {
        int r = rbase + mi * 16 + l15;
        f[mi] = *(const s8v*)(plane + r * 32 + ((quad ^ (r & 3) ^ ((r >> 2) & 3)) * 8));
    }
}

__device__ __forceinline__ void mfma_quad(f4v (&a4)[4][4], const s8v (&af)[4], const s8v (&bf)[4]) {
    __builtin_amdgcn_s_setprio(1);
#pragma unroll
    for (int mi = 0; mi < 4; ++mi)
#pragma unroll
        for (int ni = 0; ni < 4; ++ni)
            a4[mi][ni] = __builtin_amdgcn_mfma_f32_16x16x32_bf16(af[mi], bf[ni], a4[mi][ni], 0, 0, 0);
    __builtin_amdgcn_s_setprio(0);
}

// ============ kloop2ph: proven R2 core (BK=32, 4-deep circular, counted vmcnt(8)) ============
__device__ __forceinline__ void kloop2ph(const u16* __restrict__ Ag, const u16* __restrict__ Bg,
                                         int K, int NT, u16* lds8, f4v (&acc)[8][4],
                                         int t, int wm, int wn, int l15, int quad) {
#pragma unroll
    for (int T = 0; T < 3; ++T) {
        u16* Ab = lds8 + T * 16384;
        stage_plane(Ag, K, T * 32, Ab, t);
        stage_plane(Bg, K, T * 32, Ab + 8192, t);
    }
    asm volatile("s_waitcnt vmcnt(8)" ::: "memory");
    __builtin_amdgcn_s_barrier();

    s8v bf[4];
    for (int T = 0; T < NT; ++T) {
        const u16* Ab = lds8 + (T & 3) * 16384;
        const u16* Bb = Ab + 8192;
        u16* Sb = lds8 + ((T + 3) & 3) * 16384;
        const bool st = (T < NT - 3);
        // ---- phase 0: B-frags + A-frags 0..3, stage next A-half ----
        s8v af[4];
        read_frag4(Bb, bf, wn * 64, l15, quad);
        read_frag4(Ab, af, wm * 128, l15, quad);
        if (st) stage_plane(Ag, K, (T + 3) * 32, Sb, t);
        __builtin_amdgcn_s_setprio(1);
#pragma unroll
        for (int mi = 0; mi < 4; ++mi)
#pragma unroll
            for (int ni = 0; ni < 4; ++ni)
                acc[mi][ni] = __builtin_amdgcn_mfma_f32_16x16x32_bf16(af[mi], bf[ni], acc[mi][ni], 0, 0, 0);
        __builtin_amdgcn_s_setprio(0);
        __builtin_amdgcn_s_barrier();
        // ---- phase 1: A-frags 4..7, stage next B-half ----
        read_frag4(Ab, af, wm * 128 + 64, l15, quad);
        if (st) stage_plane(Bg, K, (T + 3) * 32, Sb + 8192, t);
        __builtin_amdgcn_s_setprio(1);
#pragma unroll
        for (int mi = 0; mi < 4; ++mi)
#pragma unroll
            for (int ni = 0; ni < 4; ++ni)
                acc[4 + mi][ni] = __builtin_amdgcn_mfma_f32_16x16x32_bf16(af[mi], bf[ni], acc[4 + mi][ni], 0, 0, 0);
        __builtin_amdgcn_s_setprio(0);
        if (T < NT - 3)       asm volatile("s_waitcnt vmcnt(8)" ::: "memory");
        else if (T == NT - 3) asm volatile("s_waitcnt vmcnt(4)" ::: "memory");
        else if (T == NT - 2) asm volatile("s_waitcnt vmcnt(0)" ::: "memory");
        __builtin_amdgcn_s_barrier();
    }
}

// ============ kloop8: m201-style 8-phase (BK=64, 2 K-tile dbuf, counted vmcnt(4)) ============
// R4 layout minus the lgkmcnt(0)+sched_barrier pins (m141 lesson): compiler places its own
// fine-grained lgkm waits before MFMA uses. Raw barriers + setprio + counted vmcnt only.
// LDS: buf b at b*32768; A.ks0 +0, A.ks1 +8192, B.ks0 +16384, B.ks1 +24576 (u16 offsets).
// K-tile j stages: p1 A.ks1(j+1), p2 B.ks1(j+1) (regions last read p3/p4 of j-1);
//                  p3 A.ks0(j+2), p4 B.ks0(j+2) (regions freed after p2 of j).
// vmcnt(4) at p4(j) -> p1/p2 stages landed before their reads at p3(j+1); p3/p4 before p1(j+2).
__device__ __forceinline__ void kloop8(const u16* __restrict__ Ag, const u16* __restrict__ Bg,
                                       int K, int NT, u16* lds, f4v (&acc)[2][4][4],
                                       int t, int wm, int wn, int l15, int quad) {
    stage_plane(Ag, K, 0,  lds, t);                    // A buf0 ks0
    stage_plane(Bg, K, 0,  lds + 16384, t);            // B buf0 ks0
    stage_plane(Ag, K, 32, lds + 8192, t);             // A buf0 ks1
    stage_plane(Bg, K, 32, lds + 24576, t);            // B buf0 ks1
    stage_plane(Ag, K, 64, lds + 32768, t);            // A buf1 ks0
    stage_plane(Bg, K, 64, lds + 32768 + 16384, t);    // B buf1 ks0
    asm volatile("s_waitcnt vmcnt(4)" ::: "memory");
    __builtin_amdgcn_s_barrier();

    const int ab0 = wm * 128, ab1 = wm * 128 + 64, bb = wn * 64;
    s8v af[4], bf[4];
    for (int j = 0; j < NT; ++j) {
        u16* cur = lds + (j & 1) * 32768;
        u16* nxt = lds + ((j + 1) & 1) * 32768;
        const u16* Ak0 = cur;
        const u16* Ak1 = cur + 8192;
        const u16* Bk0 = cur + 16384;
        const u16* Bk1 = cur + 24576;
        const bool s1 = (j + 1 < NT), s2 = (j + 2 < NT);

        // ---- p1: ks0, mg0 ----
        read_frag4(Bk0, bf, bb, l15, quad);
        read_frag4(Ak0, af, ab0, l15, quad);
        if (s1) stage_plane(Ag, K, (j + 1) * 64 + 32, nxt + 8192, t);       // A.ks1(j+1)
        __builtin_amdgcn_s_barrier();
        mfma_quad(acc[0], af, bf);
        __builtin_amdgcn_s_barrier();
        // ---- p2: ks0, mg1 (bf reused in regs) ----
        read_frag4(Ak0, af, ab1, l15, quad);
        if (s1) stage_plane(Bg, K, (j + 1) * 64 + 32, nxt + 24576, t);      // B.ks1(j+1)
        __builtin_amdgcn_s_barrier();
        mfma_quad(acc[1], af, bf);
        __builtin_amdgcn_s_barrier();
        // ---- p3: ks1, mg0 ----
        read_frag4(Bk1, bf, bb, l15, quad);
        read_frag4(Ak1, af, ab0, l15, quad);
        if (s2) stage_plane(Ag, K, (j + 2) * 64, cur, t);                   // A.ks0(j+2)
        __builtin_amdgcn_s_barrier();
        mfma_quad(acc[0], af, bf);
        __builtin_amdgcn_s_barrier();
        // ---- p4: ks1, mg1 ----
        read_frag4(Ak1, af, ab1, l15, quad);
        if (s2) stage_plane(Bg, K, (j + 2) * 64, cur + 16384, t);           // B.ks0(j+2)
        if (j < NT - 2) asm volatile("s_waitcnt vmcnt(4)" ::: "memory");
        else            asm volatile("s_waitcnt vmcnt(0)" ::: "memory");
        __builtin_amdgcn_s_barrier();
        mfma_quad(acc[1], af, bf);
        __builtin_amdgcn_s_barrier();
    }
}

// ---------- constants ----------
// DIM=1024, HID=2048, QK=128, G=256, NG=16, B=4, ROWS=16384
// I/O fp32; intermediates bf16. heads: 0=quad_q 1=lin_q 2=quad_k 3=lin_k

// ---------- fp32 -> bf16 transpose (weights) ----------
__global__ __launch_bounds__(256) void convT_kernel(const float* __restrict__ in,
                                                    u16* __restrict__ out, int K, int N) {
    __shared__ float tile[32][33];
    int k0 = blockIdx.y * 32, n0 = blockIdx.x * 32;
    int t = threadIdx.x;
    int r = t >> 5, c = t & 31;
#pragma unroll
    for (int rr = r; rr < 32; rr += 8) tile[rr][c] = in[(size_t)(k0 + rr) * N + n0 + c];
    __syncthreads();
#pragma unroll
    for (int rr = r; rr < 32; rr += 8) out[(size_t)(n0 + rr) * K + k0 + c] = f2b(tile[c][rr]);
}

// ---------- LayerNorm: fp32 in -> bf16 out ----------
__global__ __launch_bounds__(256) void ln_kernel(const float* __restrict__ x,
                                                 const float* __restrict__ w,
                                                 const float* __restrict__ bsh,
                                                 u16* __restrict__ out) {
    int row = blockIdx.x, t = threadIdx.x;
    const float* xr = x + (size_t)row * 1024;
    float4 u = *reinterpret_cast<const float4*>(xr + t * 4);
    float s = u.x + u.y + u.z + u.w;
    float s2 = u.x * u.x + u.y * u.y + u.z * u.z + u.w * u.w;
#pragma unroll
    for (int o = 32; o; o >>= 1) {
        s += __shfl_down(s, o, 64);
        s2 += __shfl_down(s2, o, 64);
    }
    __shared__ float rs[4], rs2[4];
    int wid = t >> 6;
    if ((t & 63) == 0) { rs[wid] = s; rs2[wid] = s2; }
    __syncthreads();
    float S = rs[0] + rs[1] + rs[2] + rs[3];
    float S2 = rs2[0] + rs2[1] + rs2[2] + rs2[3];
    float mu = S * (1.0f / 1024.0f);
    float var = S2 * (1.0f / 1024.0f) - mu * mu;
    float rinv = rsqrtf(var + 1e-5f);
    float4 uw = *reinterpret_cast<const float4*>(w + t * 4);
    float4 ub = *reinterpret_cast<const float4*>(bsh + t * 4);
    ushort4 o;
    o.x = f2b((u.x - mu) * rinv * uw.x + ub.x);
    o.y = f2b((u.y - mu) * rinv * uw.y + ub.y);
    o.z = f2b((u.z - mu) * rinv * uw.z + ub.z);
    o.w = f2b((u.w - mu) * rinv * uw.w + ub.w);
    *reinterpret_cast<ushort4*>(out + (size_t)row * 1024 + t * 4) = o;
}

// ---------- Wh GEMM (256^2 8-phase): silu(normed @ WhT^T + bh) -> vT | gate ----------
__global__ __launch_bounds__(512) void gemm_hv256(const u16* __restrict__ A,
                                                  const u16* __restrict__ Bt,
                                                  const float* __restrict__ bias,
                                                  u16* __restrict__ vT,
                                                  u16* __restrict__ gate) {
    __shared__ __align__(16) u16 lds8[65536];   // 128 KB
    const int t = threadIdx.x;
    const int lane = t & 63, w = t >> 6;
    const int wm = w >> 2, wn = w & 3;
    const int l15 = lane & 15, quad = lane >> 4;

    int wg = blockIdx.x;                 // nwg = 1024, XCD-bijective swizzle (1024%8==0)
    wg = (wg & 7) * 128 + (wg >> 3);
    const int by = wg >> 4, bx = wg & 15;
    const int m0 = by * 256, n0 = bx * 256;

    f4v acc[2][4][4] = {};
    kloop8(A + (size_t)m0 * 1024, Bt + (size_t)n0 * 1024, 1024, 16,
           lds8, acc, t, wm, wn, l15, quad);

    const bool isV = (n0 < 2048);
    const int bg = by;                   // 256-row tiles align with groups
#pragma unroll
    for (int ni = 0; ni < 4; ++ni) {
        int n = n0 + wn * 64 + ni * 16 + l15;
        float bs = bias[n];
#pragma unroll
        for (int mg = 0; mg < 2; ++mg) {
#pragma unroll
            for (int m = 0; m < 4; ++m) {
                int mloc = wm * 128 + (mg * 4 + m) * 16 + quad * 4;
                if (isV) {
                    ushort4 o;
                    o.x = f2b(silu_f(acc[mg][m][ni][0] + bs));
                    o.y = f2b(silu_f(acc[mg][m][ni][1] + bs));
                    o.z = f2b(silu_f(acc[mg][m][ni][2] + bs));
                    o.w = f2b(silu_f(acc[mg][m][ni][3] + bs));
                    *reinterpret_cast<ushort4*>(vT + ((size_t)bg * 2048 + n) * 256 + mloc) = o;
                } else {
#pragma unroll
                    for (int reg = 0; reg < 4; ++reg)
                        gate[(size_t)(m0 + mloc + reg) * 2048 + (n - 2048)] =
                            f2b(silu_f(acc[mg][m][ni][reg] + bs));
                }
            }
        }
    }
}

// ---------- final GEMM (256^2 2-phase, R2-proven): gated @ WoutT^T + bout + x -> fp32 out ----------
__global__ __launch_bounds__(512) void gemm_out256(const u16* __restrict__ A,
                                                   const u16* __restrict__ Bt,
                                                   const float* __restrict__ bias,
                                                   const float* __restrict__ resid,
                                                   float* __restrict__ C) {
    __shared__ __align__(16) u16 lds8[65536];
    const int t = threadIdx.x;
    const int lane = t & 63, w = t >> 6;
    const int wm = w >> 2, wn = w & 3;
    const int l15 = lane & 15, quad = lane >> 4;

    int wg = blockIdx.x;                 // nwg = 256, swizzle (256%8==0)
    wg = (wg & 7) * 32 + (wg >> 3);
    const int by = wg >> 2, bx = wg & 3;
    const int m0 = by * 256, n0 = bx * 256;

    f4v acc[8][4] = {};
    kloop2ph(A + (size_t)m0 * 2048, Bt + (size_t)n0 * 2048, 2048, 64,
             lds8, acc, t, wm, wn, l15, quad);

#pragma unroll
    for (int ni = 0; ni < 4; ++ni) {
        int n = n0 + wn * 64 + ni * 16 + l15;
        float bs = bias[n];
#pragma unroll
        for (int mi = 0; mi < 8; ++mi) {
#pragma unroll
            for (int reg = 0; reg < 4; ++reg) {
                int m = m0 + wm * 128 + mi * 16 + quad * 4 + reg;
                C[(size_t)m * 1024 + n] = acc[mi][ni][reg] + bs + resid[(size_t)m * 1024 + n];
            }
        }
    }
}

// ---------- qk projection MFMA GEMM: silu(normed @ WqkT^T + bqk) -> qk [16384][128] ----------
__global__ __launch_bounds__(256) void gemm_qk(const u16* __restrict__ A,
                                               const u16* __restrict__ Bt,
                                               const float* __restrict__ bias,
                                               u16* __restrict__ C) {
    __shared__ __align__(16) u16 Al[128 * 64];
    __shared__ __align__(16) u16 Bl[128 * 64];
    const int t = threadIdx.x;
    const int lane = t & 63, w = t >> 6;
    const int wr = w >> 1, wc = w & 1;
    const int l15 = lane & 15, quad = lane >> 4, l7 = lane & 7;
    const int m0 = blockIdx.y * 128;    // N fixed at 128 -> n0 = 0
    const int sr = t >> 3, ss = t & 7;

    f4v acc[4][4] = {};
    for (int k0 = 0; k0 < 1024; k0 += 64) {
#pragma unroll
        for (int i = 0; i < 4; ++i) {
            int r = i * 32 + sr;
            int q = ss ^ (r & 7);
            gld16(A + (size_t)(m0 + r) * 1024 + q * 8 + k0, Al + i * 2048 + t * 8);
            gld16(Bt + (size_t)r * 1024 + q * 8 + k0, Bl + i * 2048 + t * 8);
        }
        __syncthreads();
        mfma_block(Al, Bl, acc, wr, wc, l15, quad, l7);
        __syncthreads();
    }
#pragma unroll
    for (int ni = 0; ni < 4; ++ni) {
        int n = wc * 64 + ni * 16 + l15;
        float bs = bias[n];
#pragma unroll
        for (int mi = 0; mi < 4; ++mi) {
#pragma unroll
            for (int reg = 0; reg < 4; ++reg) {
                int m = m0 + wr * 64 + mi * 16 + quad * 4 + reg;
                C[(size_t)m * 128 + n] = f2b(silu_f(acc[mi][ni][reg] + bs));
            }
        }
    }
}

// ---------- lin_k transpose+scale: klT[bg][d][j] = b2f(qk[bg*256+j][d]) * w3[d] + b3[d] ----------
__global__ __launch_bounds__(256) void klT_kernel(const u16* __restrict__ qk,
                                                  const float* __restrict__ qk_w,
                                                  const float* __restrict__ qk_b,
                                                  u16* __restrict__ klT) {
    __shared__ __align__(16) u16 tile[64][128];
    const int bg = blockIdx.x >> 2, jc = (blockIdx.x & 3) * 64;
    const int t = threadIdx.x;
    const int r = t >> 4, c = (t & 15) * 8;
#pragma unroll
    for (int rr = 0; rr < 64; rr += 16)
        *(s8v*)(&tile[r + rr][c]) =
            *(const s8v*)(qk + (size_t)(bg * 256 + jc + r + rr) * 128 + c);
    __syncthreads();
    const int d = t & 127, jb = (t >> 7) * 32;
    const float kw = qk_w[3 * 128 + d], kb = qk_b[3 * 128 + d];
    s8v ov[4];
#pragma unroll
    for (int q = 0; q < 4; ++q)
#pragma unroll
        for (int j = 0; j < 8; ++j)
            ov[q][j] = (short)f2b(b2f(tile[jb + q * 8 + j][d]) * kw + kb);
    u16* dst = klT + ((size_t)bg * 128 + d) * 256 + jc + jb;
#pragma unroll
    for (int q = 0; q < 4; ++q) *(s8v*)(dst + q * 8) = ov[q];
}

// ---------- scores: Sbuf[bg][i][0..255] = relu^2(qq.kk^T/256 + t5bias, causal), [256..383] = lq ----------
__global__ __launch_bounds__(256) void scores_kernel(const u16* __restrict__ qk,
                                                     const float* __restrict__ qk_w,
                                                     const float* __restrict__ qk_b,
                                                     const float* __restrict__ rel_table,
                                                     u16* __restrict__ Sbuf) {
    __shared__ __align__(16) u16 qkl[256 * 128];   // raw qk rows for this group (64KB)
    __shared__ float biasn[256];
    __shared__ float w0[128], b0[128], w1[128], b1[128], w2[128], b2v[128];
    const int t = threadIdx.x;
    const int bg = blockIdx.x >> 1, mt = blockIdx.x & 1;
    const int lane = t & 63, w = t >> 6;
    const int wr = w >> 1, wc = w & 1;
    const int l15 = lane & 15, quad = lane >> 4;

    if (t < 128) {
        w0[t] = qk_w[t];        b0[t] = qk_b[t];
        w1[t] = qk_w[128 + t];  b1[t] = qk_b[128 + t];
        w2[t] = qk_w[256 + t];  b2v[t] = qk_b[256 + t];
    }
    {
        int n = t;
        int bucket;
        if (n < 16) bucket = n;
        else {
            float v = logf((float)n / 16.0f) / 2.0794415416798357f * 16.0f;
            int vl = 16 + (int)v;
            bucket = vl > 31 ? 31 : vl;
        }
        biasn[n] = rel_table[bucket] * 11.313708498984761f;
    }
    // stage all 256 rows x 128 cols of this group's qk
#pragma unroll
    for (int it = 0; it < 16; ++it) {
        int r = (t >> 4) + it * 16, c = (t & 15) * 8;
        *(s8v*)(qkl + r * 128 + c) = *(const s8v*)(qk + ((size_t)(bg * 256 + r)) * 128 + c);
    }
    __syncthreads();

    // wave tile: 64 m-rows x 128 n-cols; block: 128 rows (mt) x 256 cols
    f4v acc[4][8] = {};
#pragma unroll
    for (int kstep = 0; kstep < 4; ++kstep) {
        int kc = kstep * 32 + quad * 8;
        float w0f[8], b0f[8], w2f[8], b2f_[8];
#pragma unroll
        for (int j = 0; j < 8; ++j) {
            w0f[j] = w0[kc + j]; b0f[j] = b0[kc + j];
            w2f[j] = w2[kc + j]; b2f_[j] = b2v[kc + j];
        }
        s8v af[4];
#pragma unroll
        for (int mi = 0; mi < 4; ++mi) {
            int ra = mt * 128 + wr * 64 + mi * 16 + l15;
            s8v raw = *(const s8v*)(qkl + ra * 128 + kc);
#pragma unroll
            for (int j = 0; j < 8; ++j) af[mi][j] = (short)f2b(b2f((u16)raw[j]) * w0f[j] + b0f[j]);
        }
#pragma unroll
        for (int np = 0; np < 2; ++np) {
            s8v bf[4];
#pragma unroll
            for (int ni = 0; ni < 4; ++ni) {
                int rb = wc * 128 + (np * 4 + ni) * 16 + l15;
                s8v raw = *(const s8v*)(qkl + rb * 128 + kc);
#pragma unroll
                for (int j = 0; j < 8; ++j) bf[ni][j] = (short)f2b(b2f((u16)raw[j]) * w2f[j] + b2f_[j]);
            }
#pragma unroll
            for (int mi = 0; mi < 4; ++mi)
#pragma unroll
                for (int ni = 0; ni < 4; ++ni)
                    acc[mi][np * 4 + ni] = __builtin_amdgcn_mfma_f32_16x16x32_bf16(af[mi], bf[ni], acc[mi][np * 4 + ni], 0, 0, 0);
        }
    }
    // epilogue: bias + relu^2 + causal -> bf16 Sbuf
#pragma unroll
    for (int ni = 0; ni < 8; ++ni) {
        int gj = wc * 128 + ni * 16 + l15;
#pragma unroll
        for (int mi = 0; mi < 4; ++mi) {
#pragma unroll
            for (int reg = 0; reg < 4; ++reg) {
                int gi = mt * 128 + wr * 64 + mi * 16 + quad * 4 + reg;
                float aval = 0.0f;
                if (gj <= gi) {
                    float sv = acc[mi][ni][reg] * (1.0f / 256.0f) + biasn[gi - gj];
                    sv = fmaxf(sv, 0.0f);
                    aval = sv * sv;
                }
                Sbuf[((size_t)bg * 256 + gi) * 384 + gj] = f2b(aval);
            }
        }
    }
    // lq columns 256..383
#pragma unroll
    for (int it = 0; it < 8; ++it) {
        int i = mt * 128 + (t >> 4) + it * 16;
        int d = (t & 15) * 8;
        s8v raw = *(const s8v*)(qkl + i * 128 + d);
        u16* dst = Sbuf + ((size_t)bg * 256 + i) * 384 + 256 + d;
#pragma unroll
        for (int j = 0; j < 8; ++j)
            dst[j] = f2b(b2f((u16)raw[j]) * w1[d + j] + b1[d + j]);
    }
}

// ---------- per-group kv MFMA GEMM: kvT[e][d] = (1/256) * sum_j vT[e][j] * klT[d][j] ----------
__global__ __launch_bounds__(256) void kv_gemm(const u16* __restrict__ vT,
                                               const u16* __restrict__ klT,
                                               u16* __restrict__ kvT) {
    __shared__ __align__(16) u16 Al[128 * 64];
    __shared__ __align__(16) u16 Bl[128 * 64];
    const int t = threadIdx.x;
    const int lane = t & 63, w = t >> 6;
    const int wr = w >> 1, wc = w & 1;
    const int l15 = lane & 15, quad = lane >> 4, l7 = lane & 7;
    const int bg = blockIdx.y, m0 = blockIdx.x * 128;   // m = e, n = d (128 total)
    const int sr = t >> 3, ss = t & 7;

    const u16* Av = vT + (size_t)bg * 2048 * 256;
    const u16* Bk = klT + (size_t)bg * 128 * 256;

    f4v acc[4][4] = {};
    for (int k0 = 0; k0 < 256; k0 += 64) {
#pragma unroll
        for (int i = 0; i < 4; ++i) {
            int r = i * 32 + sr;
            int q = ss ^ (r & 7);
            gld16(Av + (size_t)(m0 + r) * 256 + q * 8 + k0, Al + i * 2048 + t * 8);
            gld16(Bk + (size_t)r * 256 + q * 8 + k0, Bl + i * 2048 + t * 8);
        }
        __syncthreads();
        mfma_block(Al, Bl, acc, wr, wc, l15, quad, l7);
        __syncthreads();
    }
#pragma unroll
    for (int ni = 0; ni < 4; ++ni) {
        int n = wc * 64 + ni * 16 + l15;
#pragma unroll
        for (int mi = 0; mi < 4; ++mi) {
#pragma unroll
            for (int reg = 0; reg < 4; ++reg) {
                int m = m0 + wr * 64 + mi * 16 + quad * 4 + reg;
                kvT[((size_t)bg * 2048 + m) * 128 + n] = f2b(acc[mi][ni][reg] * (1.0f / 256.0f));
            }
        }
    }
}

// ---------- shifted cumsum over groups (in-place, kvT layout [b][g][e][d]) ----------
__global__ __launch_bounds__(256) void prefix_kernel(u16* __restrict__ kvT) {
    size_t tid = (size_t)blockIdx.x * 256 + threadIdx.x;  // 1,048,576
    int d = (int)(tid & 127);
    int e = (int)((tid >> 7) & 2047);
    int b = (int)(tid >> 18);
    size_t base = ((size_t)(b * 16) * 2048 + e) * 128 + d;
    const size_t gs = 2048 * 128;
    float vals[16];
#pragma unroll
    for (int g = 0; g < 16; ++g) vals[g] = b2f(kvT[base + (size_t)g * gs]);
    float s = 0.0f;
#pragma unroll
    for (int g = 0; g < 16; ++g) {
        kvT[base + (size_t)g * gs] = f2b(s);
        s += vals[g];
    }
}

// ---------- attention GEMM: out = [S|lq] @ [v;kv], times gate, in place over gate ----------
__global__ __launch_bounds__(256) void attn_gemm(const u16* __restrict__ Sbuf,
                                                 const u16* __restrict__ vT,
                                                 const u16* __restrict__ kvT,
                                                 u16* __restrict__ gate) {
    __shared__ __align__(16) u16 Al[128 * 64];
    __shared__ __align__(16) u16 Bl[128 * 64];
    const int t = threadIdx.x;
    const int lane = t & 63, w = t >> 6;
    const int wr = w >> 1, wc = w & 1;
    const int l15 = lane & 15, quad = lane >> 4, l7 = lane & 7;
    const int bg = blockIdx.y >> 1, mt = blockIdx.y & 1;
    const int n0 = blockIdx.x * 128;   // e offset
    const int sr = t >> 3, ss = t & 7;

    const u16* Abase = Sbuf + ((size_t)bg * 256 + mt * 128) * 384;
    const u16* Bv = vT + (size_t)bg * 2048 * 256;
    const u16* Bk = kvT + (size_t)bg * 2048 * 128;

    f4v acc[4][4] = {};
    // phase 1: K=256 (S @ v)
    for (int k0 = 0; k0 < 256; k0 += 64) {
#pragma unroll
        for (int i = 0; i < 4; ++i) {
            int r = i * 32 + sr;
            int q = ss ^ (r & 7);
            gld16(Abase + (size_t)r * 384 + q * 8 + k0, Al + i * 2048 + t * 8);
            gld16(Bv + (size_t)(n0 + r) * 256 + q * 8 + k0, Bl + i * 2048 + t * 8);
        }
        __syncthreads();
        mfma_block(Al, Bl, acc, wr, wc, l15, quad, l7);
        __syncthreads();
    }
    // phase 2: K=128 (lq @ kv_pref)
    for (int k0 = 0; k0 < 128; k0 += 64) {
#pragma unroll
        for (int i = 0; i < 4; ++i) {
            int r = i * 32 + sr;
            int q = ss ^ (r & 7);
            gld16(Abase + (size_t)r * 384 + 256 + q * 8 + k0, Al + i * 2048 + t * 8);
            gld16(Bk + (size_t)(n0 + r) * 128 + q * 8 + k0, Bl + i * 2048 + t * 8);
        }
        __syncthreads();
        mfma_block(Al, Bl, acc, wr, wc, l15, quad, l7);
        __syncthreads();
    }
    // epilogue: multiply by gate, write gated in place
#pragma unroll
    for (int ni = 0; ni < 4; ++ni) {
        int e = n0 + wc * 64 + ni * 16 + l15;
#pragma unroll
        for (int mi = 0; mi < 4; ++mi) {
#pragma unroll
            for (int reg = 0; reg < 4; ++reg) {
                int gi = mt * 128 + wr * 64 + mi * 16 + quad * 4 + reg;
                u16* p = gate + ((size_t)bg * 256 + gi) * 2048 + e;
                *p = f2b(acc[mi][ni][reg] * b2f(*p));
            }
        }
    }
}

// ---------- launch ----------
extern "C" void kernel_launch(void* const* d_in, const int* in_sizes, int n_in,
                              void* d_out, int out_size, void* d_ws, size_t ws_size,
                              hipStream_t stream) {
    const float* x = (const float*)d_in[0];
    const float* ln_w = (const float*)d_in[1];
    const float* ln_b = (const float*)d_in[2];
    const float* Wh = (const float*)d_in[3];
    const float* bh = (const float*)d_in[4];
    const float* Wqk = (const float*)d_in[5];
    const float* bqk = (const float*)d_in[6];
    const float* qk_w = (const float*)d_in[7];
    const float* qk_b = (const float*)d_in[8];
    const float* rel_table = (const float*)d_in[9];
    const float* Wout = (const float*)d_in[10];
    const float* bout = (const float*)d_in[11];
    float* out = (float*)d_out;

    char* ws = (char*)d_ws;
    u16* normed = (u16*)(ws);                  // 32 MB (dead after projections)
    u16* kvT    = (u16*)(ws);                  // aliases normed: [64][2048][128] 32 MB
    u16* gate   = (u16*)(ws + 33554432ull);    // [16384][2048] 64 MB (gate -> gated)
    u16* vT     = (u16*)(ws + 100663296ull);   // [64][2048][256] 64 MB
    u16* qk     = (u16*)(ws + 167772160ull);   // [16384][128] 4 MB
    u16* WhT    = (u16*)(ws + 171966464ull);   // [4096][1024] 8 MB (dead after gemm_hv)
    u16* klT    = (u16*)(ws + 171966464ull);   // aliases WhT: [64][128][256] 4 MB
    u16* WoutT  = (u16*)(ws + 180355072ull);   // [1024][2048] 4 MB
    u16* Sbuf   = (u16*)(ws + 184549376ull);   // [64][256][384] 12,582,912 B
    u16* WqkT   = (u16*)(ws + 184549376ull);   // aliases Sbuf head: [128][1024] 256 KB (dead before scores)
    // total = 197,132,288 B (~188 MiB)

    convT_kernel<<<dim3(128, 32), 256, 0, stream>>>(Wh, WhT, 1024, 4096);
    convT_kernel<<<dim3(32, 64), 256, 0, stream>>>(Wout, WoutT, 2048, 1024);
    convT_kernel<<<dim3(4, 32), 256, 0, stream>>>(Wqk, WqkT, 1024, 128);
    ln_kernel<<<16384, 256, 0, stream>>>(x, ln_w, ln_b, normed);
    gemm_hv256<<<1024, 512, 0, stream>>>(normed, WhT, bh, vT, gate);
    gemm_qk<<<dim3(1, 128), 256, 0, stream>>>(normed, WqkT, bqk, qk);
    klT_kernel<<<256, 256, 0, stream>>>(qk, qk_w, qk_b, klT);
    scores_kernel<<<128, 256, 0, stream>>>(qk, qk_w, qk_b, rel_table, Sbuf);
    kv_gemm<<<dim3(16, 64), 256, 0, stream>>>(vT, klT, kvT);
    prefix_kernel<<<4096, 256, 0, stream>>>(kvT);
    attn_gemm<<<dim3(16, 128), 256, 0, stream>>>(Sbuf, vT, kvT, gate);
    gemm_out256<<<256, 512, 0, stream>>>(gate, WoutT, bout, x, out);
}

// Round 7
// 574.091 us; speedup vs baseline: 3.0197x; 1.0060x over previous
//
#include <hip/hip_runtime.h>
#include <hip/hip_bf16.h>

typedef unsigned short u16;
typedef short s8v __attribute__((ext_vector_type(8)));   // 8 bf16 as i16 (4 VGPRs)
typedef float f4v __attribute__((ext_vector_type(4)));   // MFMA 16x16 accumulator

// ---------- helpers ----------
__device__ __forceinline__ float b2f(u16 u) { return __uint_as_float(((unsigned)u) << 16); }
__device__ __forceinline__ u16 f2b(float f) {
    unsigned u = __float_as_uint(f);
    unsigned r = 0x7FFFu + ((u >> 16) & 1u);
    return (u16)((u + r) >> 16);
}
__device__ __forceinline__ float silu_f(float x) { return x / (1.0f + expf(-x)); }

__device__ __forceinline__ void gld16(const u16* g, u16* l) {
    __builtin_amdgcn_global_load_lds((const __attribute__((address_space(1))) unsigned*)g,
                                     (__attribute__((address_space(3))) unsigned*)l, 16, 0, 0);
}

// shared MFMA inner block: BK=64 staged in Al/Bl (XOR-swizzled), 4x4 16x16 tiles/wave
__device__ __forceinline__ void mfma_block(const u16* Al, const u16* Bl, f4v acc[4][4],
                                           int wr, int wc, int l15, int quad, int l7) {
#pragma unroll
    for (int ks = 0; ks < 2; ++ks) {
        s8v af[4], bf[4];
        int cch = ((ks * 4 + quad) ^ l7) * 8;
#pragma unroll
        for (int mi = 0; mi < 4; ++mi)
            af[mi] = *(const s8v*)(Al + (wr * 64 + mi * 16 + l15) * 64 + cch);
#pragma unroll
        for (int ni = 0; ni < 4; ++ni)
            bf[ni] = *(const s8v*)(Bl + (wc * 64 + ni * 16 + l15) * 64 + cch);
#pragma unroll
        for (int mi = 0; mi < 4; ++mi)
#pragma unroll
            for (int ni = 0; ni < 4; ++ni)
                acc[mi][ni] = __builtin_amdgcn_mfma_f32_16x16x32_bf16(af[mi], bf[ni], acc[mi][ni], 0, 0, 0);
    }
}

// ============ shared 256-wide staging (LDS plane [256][32] u16, XOR-swizzled) ============
// chunk swizzle: c ^ (row&3) ^ ((row>>2)&3) -> wave64 b128 reads hit the 2-lane/bank floor.
__device__ __forceinline__ void stage_plane(const u16* __restrict__ src, int K, int kbase,
                                            u16* dst, int t) {
    const int row = t >> 2, ch = t & 3;
    const int csw = (ch ^ (row & 3) ^ ((row >> 2) & 3)) * 8;   // (row+128) -> same swizzle
    gld16(src + (size_t)row * K + kbase + csw, dst + row * 32 + ch * 8);
    gld16(src + (size_t)(row + 128) * K + kbase + csw, dst + (row + 128) * 32 + ch * 8);
}

__device__ __forceinline__ void read_frag4(const u16* plane, s8v (&f)[4], int rbase, int l15, int quad) {
#pragma unroll
    for (int mi = 0; mi < 4; ++mi) {
        int r = rbase + mi * 16 + l15;
        f[mi] = *(const s8v*)(plane + r * 32 + ((quad ^ (r & 3) ^ ((r >> 2) & 3)) * 8));
    }
}

// ============ kloop2ph: proven core (BK=32, 4-deep circular, counted vmcnt(8)) ============
// Measured 619 TF @ K=1024 (R2/R3). Tile T staged during T-3 into buf[T&3] (last read T-4).
__device__ __forceinline__ void kloop2ph(const u16* __restrict__ Ag, const u16* __restrict__ Bg,
                                         int K, int NT, u16* lds8, f4v (&acc)[8][4],
                                         int t, int wm, int wn, int l15, int quad) {
#pragma unroll
    for (int T = 0; T < 3; ++T) {
        u16* Ab = lds8 + T * 16384;
        stage_plane(Ag, K, T * 32, Ab, t);
        stage_plane(Bg, K, T * 32, Ab + 8192, t);
    }
    asm volatile("s_waitcnt vmcnt(8)" ::: "memory");
    __builtin_amdgcn_s_barrier();

    s8v bf[4];
    for (int T = 0; T < NT; ++T) {
        const u16* Ab = lds8 + (T & 3) * 16384;
        const u16* Bb = Ab + 8192;
        u16* Sb = lds8 + ((T + 3) & 3) * 16384;
        const bool st = (T < NT - 3);
        // ---- phase 0: B-frags + A-frags 0..3, stage next A-half ----
        s8v af[4];
        read_frag4(Bb, bf, wn * 64, l15, quad);
        read_frag4(Ab, af, wm * 128, l15, quad);
        if (st) stage_plane(Ag, K, (T + 3) * 32, Sb, t);
        __builtin_amdgcn_s_setprio(1);
#pragma unroll
        for (int mi = 0; mi < 4; ++mi)
#pragma unroll
            for (int ni = 0; ni < 4; ++ni)
                acc[mi][ni] = __builtin_amdgcn_mfma_f32_16x16x32_bf16(af[mi], bf[ni], acc[mi][ni], 0, 0, 0);
        __builtin_amdgcn_s_setprio(0);
        __builtin_amdgcn_s_barrier();
        // ---- phase 1: A-frags 4..7, stage next B-half ----
        read_frag4(Ab, af, wm * 128 + 64, l15, quad);
        if (st) stage_plane(Bg, K, (T + 3) * 32, Sb + 8192, t);
        __builtin_amdgcn_s_setprio(1);
#pragma unroll
        for (int mi = 0; mi < 4; ++mi)
#pragma unroll
            for (int ni = 0; ni < 4; ++ni)
                acc[4 + mi][ni] = __builtin_amdgcn_mfma_f32_16x16x32_bf16(af[mi], bf[ni], acc[4 + mi][ni], 0, 0, 0);
        __builtin_amdgcn_s_setprio(0);
        if (T < NT - 3)       asm volatile("s_waitcnt vmcnt(8)" ::: "memory");
        else if (T == NT - 3) asm volatile("s_waitcnt vmcnt(4)" ::: "memory");
        else if (T == NT - 2) asm volatile("s_waitcnt vmcnt(0)" ::: "memory");
        __builtin_amdgcn_s_barrier();
    }
}

// ---------- constants ----------
// DIM=1024, HID=2048, QK=128, G=256, NG=16, B=4, ROWS=16384
// I/O fp32; intermediates bf16. heads: 0=quad_q 1=lin_q 2=quad_k 3=lin_k

// ---------- fused fp32 -> bf16 transpose for all three weight matrices (one launch) ----------
__global__ __launch_bounds__(256) void convT_all(const float* __restrict__ Wh,
                                                 const float* __restrict__ Wout,
                                                 const float* __restrict__ Wqk,
                                                 u16* __restrict__ WhT,
                                                 u16* __restrict__ WoutT,
                                                 u16* __restrict__ WqkT) {
    __shared__ float tile[32][33];
    int b = blockIdx.x;
    const float* in; u16* out; int K, N, bx, by;
    if (b < 4096)      { in = Wh;   out = WhT;   K = 1024; N = 4096; bx = b & 127; by = b >> 7; }
    else if (b < 6144) { b -= 4096; in = Wout; out = WoutT; K = 2048; N = 1024; bx = b & 31; by = b >> 5; }
    else               { b -= 6144; in = Wqk;  out = WqkT;  K = 1024; N = 128;  bx = b & 3;  by = b >> 2; }
    int k0 = by * 32, n0 = bx * 32;
    int t = threadIdx.x;
    int r = t >> 5, c = t & 31;
#pragma unroll
    for (int rr = r; rr < 32; rr += 8) tile[rr][c] = in[(size_t)(k0 + rr) * N + n0 + c];
    __syncthreads();
#pragma unroll
    for (int rr = r; rr < 32; rr += 8) out[(size_t)(n0 + rr) * K + k0 + c] = f2b(tile[c][rr]);
}

// ---------- LayerNorm: fp32 in -> bf16 out ----------
__global__ __launch_bounds__(256) void ln_kernel(const float* __restrict__ x,
                                                 const float* __restrict__ w,
                                                 const float* __restrict__ bsh,
                                                 u16* __restrict__ out) {
    int row = blockIdx.x, t = threadIdx.x;
    const float* xr = x + (size_t)row * 1024;
    float4 u = *reinterpret_cast<const float4*>(xr + t * 4);
    float s = u.x + u.y + u.z + u.w;
    float s2 = u.x * u.x + u.y * u.y + u.z * u.z + u.w * u.w;
#pragma unroll
    for (int o = 32; o; o >>= 1) {
        s += __shfl_down(s, o, 64);
        s2 += __shfl_down(s2, o, 64);
    }
    __shared__ float rs[4], rs2[4];
    int wid = t >> 6;
    if ((t & 63) == 0) { rs[wid] = s; rs2[wid] = s2; }
    __syncthreads();
    float S = rs[0] + rs[1] + rs[2] + rs[3];
    float S2 = rs2[0] + rs2[1] + rs2[2] + rs2[3];
    float mu = S * (1.0f / 1024.0f);
    float var = S2 * (1.0f / 1024.0f) - mu * mu;
    float rinv = rsqrtf(var + 1e-5f);
    float4 uw = *reinterpret_cast<const float4*>(w + t * 4);
    float4 ub = *reinterpret_cast<const float4*>(bsh + t * 4);
    ushort4 o;
    o.x = f2b((u.x - mu) * rinv * uw.x + ub.x);
    o.y = f2b((u.y - mu) * rinv * uw.y + ub.y);
    o.z = f2b((u.z - mu) * rinv * uw.z + ub.z);
    o.w = f2b((u.w - mu) * rinv * uw.w + ub.w);
    *reinterpret_cast<ushort4*>(out + (size_t)row * 1024 + t * 4) = o;
}

// ---------- Wh GEMM (256^2 kloop2ph): silu(normed @ WhT^T + bh) -> vT | gate ----------
__global__ __launch_bounds__(512) void gemm_hv256(const u16* __restrict__ A,
                                                  const u16* __restrict__ Bt,
                                                  const float* __restrict__ bias,
                                                  u16* __restrict__ vT,
                                                  u16* __restrict__ gate) {
    __shared__ __align__(16) u16 lds8[65536];   // 128 KB
    const int t = threadIdx.x;
    const int lane = t & 63, w = t >> 6;
    const int wm = w >> 2, wn = w & 3;
    const int l15 = lane & 15, quad = lane >> 4;

    int wg = blockIdx.x;                 // nwg = 1024, XCD-bijective swizzle (1024%8==0)
    wg = (wg & 7) * 128 + (wg >> 3);
    const int by = wg >> 4, bx = wg & 15;
    const int m0 = by * 256, n0 = bx * 256;

    f4v acc[8][4] = {};
    kloop2ph(A + (size_t)m0 * 1024, Bt + (size_t)n0 * 1024, 1024, 32,
             lds8, acc, t, wm, wn, l15, quad);

    const bool isV = (n0 < 2048);
    const int bg = by;                   // 256-row tiles align with groups
#pragma unroll
    for (int ni = 0; ni < 4; ++ni) {
        int n = n0 + wn * 64 + ni * 16 + l15;
        float bs = bias[n];
#pragma unroll
        for (int mi = 0; mi < 8; ++mi) {
            int mloc = wm * 128 + mi * 16 + quad * 4;
            if (isV) {
                ushort4 o;
                o.x = f2b(silu_f(acc[mi][ni][0] + bs));
                o.y = f2b(silu_f(acc[mi][ni][1] + bs));
                o.z = f2b(silu_f(acc[mi][ni][2] + bs));
                o.w = f2b(silu_f(acc[mi][ni][3] + bs));
                *reinterpret_cast<ushort4*>(vT + ((size_t)bg * 2048 + n) * 256 + mloc) = o;
            } else {
#pragma unroll
                for (int reg = 0; reg < 4; ++reg)
                    gate[(size_t)(m0 + mloc + reg) * 2048 + (n - 2048)] =
                        f2b(silu_f(acc[mi][ni][reg] + bs));
            }
        }
    }
}

// ---------- final GEMM (256^2 kloop2ph): gated @ WoutT^T + bout + x -> fp32 out ----------
__global__ __launch_bounds__(512) void gemm_out256(const u16* __restrict__ A,
                                                   const u16* __restrict__ Bt,
                                                   const float* __restrict__ bias,
                                                   const float* __restrict__ resid,
                                                   float* __restrict__ C) {
    __shared__ __align__(16) u16 lds8[65536];
    const int t = threadIdx.x;
    const int lane = t & 63, w = t >> 6;
    const int wm = w >> 2, wn = w & 3;
    const int l15 = lane & 15, quad = lane >> 4;

    int wg = blockIdx.x;                 // nwg = 256, swizzle (256%8==0)
    wg = (wg & 7) * 32 + (wg >> 3);
    const int by = wg >> 2, bx = wg & 3;
    const int m0 = by * 256, n0 = bx * 256;

    f4v acc[8][4] = {};
    kloop2ph(A + (size_t)m0 * 2048, Bt + (size_t)n0 * 2048, 2048, 64,
             lds8, acc, t, wm, wn, l15, quad);

#pragma unroll
    for (int ni = 0; ni < 4; ++ni) {
        int n = n0 + wn * 64 + ni * 16 + l15;
        float bs = bias[n];
#pragma unroll
        for (int mi = 0; mi < 8; ++mi) {
#pragma unroll
            for (int reg = 0; reg < 4; ++reg) {
                int m = m0 + wm * 128 + mi * 16 + quad * 4 + reg;
                C[(size_t)m * 1024 + n] = acc[mi][ni][reg] + bs + resid[(size_t)m * 1024 + n];
            }
        }
    }
}

// ---------- qk projection GEMM + fused lin_k transpose ----------
// qk[m][n] = silu(normed @ WqkT^T + bqk); klT[bg][d][j] = b2f(qk[bg*256+j][d])*w3[d]+b3[d]
__global__ __launch_bounds__(256) void gemm_qk(const u16* __restrict__ A,
                                               const u16* __restrict__ Bt,
                                               const float* __restrict__ bias,
                                               const float* __restrict__ qk_w,
                                               const float* __restrict__ qk_b,
                                               u16* __restrict__ C,
                                               u16* __restrict__ klT) {
    __shared__ __align__(16) u16 Al[128 * 64];
    __shared__ __align__(16) u16 Bl[128 * 64];
    const int t = threadIdx.x;
    const int lane = t & 63, w = t >> 6;
    const int wr = w >> 1, wc = w & 1;
    const int l15 = lane & 15, quad = lane >> 4, l7 = lane & 7;
    const int m0 = blockIdx.y * 128;    // N fixed at 128 -> n0 = 0
    const int sr = t >> 3, ss = t & 7;

    f4v acc[4][4] = {};
    for (int k0 = 0; k0 < 1024; k0 += 64) {
#pragma unroll
        for (int i = 0; i < 4; ++i) {
            int r = i * 32 + sr;
            int q = ss ^ (r & 7);
            gld16(A + (size_t)(m0 + r) * 1024 + q * 8 + k0, Al + i * 2048 + t * 8);
            gld16(Bt + (size_t)r * 1024 + q * 8 + k0, Bl + i * 2048 + t * 8);
        }
        __syncthreads();
        mfma_block(Al, Bl, acc, wr, wc, l15, quad, l7);
        __syncthreads();
    }
#pragma unroll
    for (int ni = 0; ni < 4; ++ni) {
        int n = wc * 64 + ni * 16 + l15;
        float bs = bias[n];
        float kw = qk_w[3 * 128 + n], kb = qk_b[3 * 128 + n];
#pragma unroll
        for (int mi = 0; mi < 4; ++mi) {
#pragma unroll
            for (int reg = 0; reg < 4; ++reg) {
                int m = m0 + wr * 64 + mi * 16 + quad * 4 + reg;
                u16 qv = f2b(silu_f(acc[mi][ni][reg] + bs));
                C[(size_t)m * 128 + n] = qv;
                klT[(((size_t)(m >> 8)) * 128 + n) * 256 + (m & 255)] = f2b(b2f(qv) * kw + kb);
            }
        }
    }
}

// ---------- scores: Sbuf[bg][i][0..255] = relu^2(qq.kk^T/256 + t5bias, causal), [256..383] = lq ----------
__global__ __launch_bounds__(256) void scores_kernel(const u16* __restrict__ qk,
                                                     const float* __restrict__ qk_w,
                                                     const float* __restrict__ qk_b,
                                                     const float* __restrict__ rel_table,
                                                     u16* __restrict__ Sbuf) {
    __shared__ __align__(16) u16 qkl[256 * 128];   // raw qk rows for this group (64KB)
    __shared__ float biasn[256];
    __shared__ float w0[128], b0[128], w1[128], b1[128], w2[128], b2v[128];
    const int t = threadIdx.x;
    const int bg = blockIdx.x >> 1, mt = blockIdx.x & 1;
    const int lane = t & 63, w = t >> 6;
    const int wr = w >> 1, wc = w & 1;
    const int l15 = lane & 15, quad = lane >> 4;

    if (t < 128) {
        w0[t] = qk_w[t];        b0[t] = qk_b[t];
        w1[t] = qk_w[128 + t];  b1[t] = qk_b[128 + t];
        w2[t] = qk_w[256 + t];  b2v[t] = qk_b[256 + t];
    }
    {
        int n = t;
        int bucket;
        if (n < 16) bucket = n;
        else {
            float v = logf((float)n / 16.0f) / 2.0794415416798357f * 16.0f;
            int vl = 16 + (int)v;
            bucket = vl > 31 ? 31 : vl;
        }
        biasn[n] = rel_table[bucket] * 11.313708498984761f;
    }
    // stage all 256 rows x 128 cols of this group's qk
#pragma unroll
    for (int it = 0; it < 16; ++it) {
        int r = (t >> 4) + it * 16, c = (t & 15) * 8;
        *(s8v*)(qkl + r * 128 + c) = *(const s8v*)(qk + ((size_t)(bg * 256 + r)) * 128 + c);
    }
    __syncthreads();

    // wave tile: 64 m-rows x 128 n-cols; block: 128 rows (mt) x 256 cols
    f4v acc[4][8] = {};
#pragma unroll
    for (int kstep = 0; kstep < 4; ++kstep) {
        int kc = kstep * 32 + quad * 8;
        float w0f[8], b0f[8], w2f[8], b2f_[8];
#pragma unroll
        for (int j = 0; j < 8; ++j) {
            w0f[j] = w0[kc + j]; b0f[j] = b0[kc + j];
            w2f[j] = w2[kc + j]; b2f_[j] = b2v[kc + j];
        }
        s8v af[4];
#pragma unroll
        for (int mi = 0; mi < 4; ++mi) {
            int ra = mt * 128 + wr * 64 + mi * 16 + l15;
            s8v raw = *(const s8v*)(qkl + ra * 128 + kc);
#pragma unroll
            for (int j = 0; j < 8; ++j) af[mi][j] = (short)f2b(b2f((u16)raw[j]) * w0f[j] + b0f[j]);
        }
#pragma unroll
        for (int np = 0; np < 2; ++np) {
            s8v bf[4];
#pragma unroll
            for (int ni = 0; ni < 4; ++ni) {
                int rb = wc * 128 + (np * 4 + ni) * 16 + l15;
                s8v raw = *(const s8v*)(qkl + rb * 128 + kc);
#pragma unroll
                for (int j = 0; j < 8; ++j) bf[ni][j] = (short)f2b(b2f((u16)raw[j]) * w2f[j] + b2f_[j]);
            }
#pragma unroll
            for (int mi = 0; mi < 4; ++mi)
#pragma unroll
                for (int ni = 0; ni < 4; ++ni)
                    acc[mi][np * 4 + ni] = __builtin_amdgcn_mfma_f32_16x16x32_bf16(af[mi], bf[ni], acc[mi][np * 4 + ni], 0, 0, 0);
        }
    }
    // epilogue: bias + relu^2 + causal -> bf16 Sbuf
#pragma unroll
    for (int ni = 0; ni < 8; ++ni) {
        int gj = wc * 128 + ni * 16 + l15;
#pragma unroll
        for (int mi = 0; mi < 4; ++mi) {
#pragma unroll
            for (int reg = 0; reg < 4; ++reg) {
                int gi = mt * 128 + wr * 64 + mi * 16 + quad * 4 + reg;
                float aval = 0.0f;
                if (gj <= gi) {
                    float sv = acc[mi][ni][reg] * (1.0f / 256.0f) + biasn[gi - gj];
                    sv = fmaxf(sv, 0.0f);
                    aval = sv * sv;
                }
                Sbuf[((size_t)bg * 256 + gi) * 384 + gj] = f2b(aval);
            }
        }
    }
    // lq columns 256..383
#pragma unroll
    for (int it = 0; it < 8; ++it) {
        int i = mt * 128 + (t >> 4) + it * 16;
        int d = (t & 15) * 8;
        s8v raw = *(const s8v*)(qkl + i * 128 + d);
        u16* dst = Sbuf + ((size_t)bg * 256 + i) * 384 + 256 + d;
#pragma unroll
        for (int j = 0; j < 8; ++j)
            dst[j] = f2b(b2f((u16)raw[j]) * w1[d + j] + b1[d + j]);
    }
}

// ---------- per-group kv MFMA GEMM: kvT[e][d] = (1/256) * sum_j vT[e][j] * klT[d][j] ----------
__global__ __launch_bounds__(256) void kv_gemm(const u16* __restrict__ vT,
                                               const u16* __restrict__ klT,
                                               u16* __restrict__ kvT) {
    __shared__ __align__(16) u16 Al[128 * 64];
    __shared__ __align__(16) u16 Bl[128 * 64];
    const int t = threadIdx.x;
    const int lane = t & 63, w = t >> 6;
    const int wr = w >> 1, wc = w & 1;
    const int l15 = lane & 15, quad = lane >> 4, l7 = lane & 7;
    const int bg = blockIdx.y, m0 = blockIdx.x * 128;   // m = e, n = d (128 total)
    const int sr = t >> 3, ss = t & 7;

    const u16* Av = vT + (size_t)bg * 2048 * 256;
    const u16* Bk = klT + (size_t)bg * 128 * 256;

    f4v acc[4][4] = {};
    for (int k0 = 0; k0 < 256; k0 += 64) {
#pragma unroll
        for (int i = 0; i < 4; ++i) {
            int r = i * 32 + sr;
            int q = ss ^ (r & 7);
            gld16(Av + (size_t)(m0 + r) * 256 + q * 8 + k0, Al + i * 2048 + t * 8);
            gld16(Bk + (size_t)r * 256 + q * 8 + k0, Bl + i * 2048 + t * 8);
        }
        __syncthreads();
        mfma_block(Al, Bl, acc, wr, wc, l15, quad, l7);
        __syncthreads();
    }
#pragma unroll
    for (int ni = 0; ni < 4; ++ni) {
        int n = wc * 64 + ni * 16 + l15;
#pragma unroll
        for (int mi = 0; mi < 4; ++mi) {
#pragma unroll
            for (int reg = 0; reg < 4; ++reg) {
                int m = m0 + wr * 64 + mi * 16 + quad * 4 + reg;
                kvT[((size_t)bg * 2048 + m) * 128 + n] = f2b(acc[mi][ni][reg] * (1.0f / 256.0f));
            }
        }
    }
}

// ---------- shifted cumsum over groups (in-place, kvT layout [b][g][e][d]) ----------
__global__ __launch_bounds__(256) void prefix_kernel(u16* __restrict__ kvT) {
    size_t tid = (size_t)blockIdx.x * 256 + threadIdx.x;  // 1,048,576
    int d = (int)(tid & 127);
    int e = (int)((tid >> 7) & 2047);
    int b = (int)(tid >> 18);
    size_t base = ((size_t)(b * 16) * 2048 + e) * 128 + d;
    const size_t gs = 2048 * 128;
    float vals[16];
#pragma unroll
    for (int g = 0; g < 16; ++g) vals[g] = b2f(kvT[base + (size_t)g * gs]);
    float s = 0.0f;
#pragma unroll
    for (int g = 0; g < 16; ++g) {
        kvT[base + (size_t)g * gs] = f2b(s);
        s += vals[g];
    }
}

// ---------- attention GEMM: out = [S|lq] @ [v;kv], times gate, in place over gate ----------
__global__ __launch_bounds__(256) void attn_gemm(const u16* __restrict__ Sbuf,
                                                 const u16* __restrict__ vT,
                                                 const u16* __restrict__ kvT,
                                                 u16* __restrict__ gate) {
    __shared__ __align__(16) u16 Al[128 * 64];
    __shared__ __align__(16) u16 Bl[128 * 64];
    const int t = threadIdx.x;
    const int lane = t & 63, w = t >> 6;
    const int wr = w >> 1, wc = w & 1;
    const int l15 = lane & 15, quad = lane >> 4, l7 = lane & 7;
    const int bg = blockIdx.y >> 1, mt = blockIdx.y & 1;
    const int n0 = blockIdx.x * 128;   // e offset
    const int sr = t >> 3, ss = t & 7;

    const u16* Abase = Sbuf + ((size_t)bg * 256 + mt * 128) * 384;
    const u16* Bv = vT + (size_t)bg * 2048 * 256;
    const u16* Bk = kvT + (size_t)bg * 2048 * 128;

    f4v acc[4][4] = {};
    // phase 1: K=256 (S @ v)
    for (int k0 = 0; k0 < 256; k0 += 64) {
#pragma unroll
        for (int i = 0; i < 4; ++i) {
            int r = i * 32 + sr;
            int q = ss ^ (r & 7);
            gld16(Abase + (size_t)r * 384 + q * 8 + k0, Al + i * 2048 + t * 8);
            gld16(Bv + (size_t)(n0 + r) * 256 + q * 8 + k0, Bl + i * 2048 + t * 8);
        }
        __syncthreads();
        mfma_block(Al, Bl, acc, wr, wc, l15, quad, l7);
        __syncthreads();
    }
    // phase 2: K=128 (lq @ kv_pref)
    for (int k0 = 0; k0 < 128; k0 += 64) {
#pragma unroll
        for (int i = 0; i < 4; ++i) {
            int r = i * 32 + sr;
            int q = ss ^ (r & 7);
            gld16(Abase + (size_t)r * 384 + 256 + q * 8 + k0, Al + i * 2048 + t * 8);
            gld16(Bk + (size_t)(n0 + r) * 128 + q * 8 + k0, Bl + i * 2048 + t * 8);
        }
        __syncthreads();
        mfma_block(Al, Bl, acc, wr, wc, l15, quad, l7);
        __syncthreads();
    }
    // epilogue: multiply by gate, write gated in place
#pragma unroll
    for (int ni = 0; ni < 4; ++ni) {
        int e = n0 + wc * 64 + ni * 16 + l15;
#pragma unroll
        for (int mi = 0; mi < 4; ++mi) {
#pragma unroll
            for (int reg = 0; reg < 4; ++reg) {
                int gi = mt * 128 + wr * 64 + mi * 16 + quad * 4 + reg;
                u16* p = gate + ((size_t)bg * 256 + gi) * 2048 + e;
                *p = f2b(acc[mi][ni][reg] * b2f(*p));
            }
        }
    }
}

// ---------- launch ----------
extern "C" void kernel_launch(void* const* d_in, const int* in_sizes, int n_in,
                              void* d_out, int out_size, void* d_ws, size_t ws_size,
                              hipStream_t stream) {
    const float* x = (const float*)d_in[0];
    const float* ln_w = (const float*)d_in[1];
    const float* ln_b = (const float*)d_in[2];
    const float* Wh = (const float*)d_in[3];
    const float* bh = (const float*)d_in[4];
    const float* Wqk = (const float*)d_in[5];
    const float* bqk = (const float*)d_in[6];
    const float* qk_w = (const float*)d_in[7];
    const float* qk_b = (const float*)d_in[8];
    const float* rel_table = (const float*)d_in[9];
    const float* Wout = (const float*)d_in[10];
    const float* bout = (const float*)d_in[11];
    float* out = (float*)d_out;

    char* ws = (char*)d_ws;
    u16* normed = (u16*)(ws);                  // 32 MB (dead after projections)
    u16* kvT    = (u16*)(ws);                  // aliases normed: [64][2048][128] 32 MB
    u16* gate   = (u16*)(ws + 33554432ull);    // [16384][2048] 64 MB (gate -> gated)
    u16* vT     = (u16*)(ws + 100663296ull);   // [64][2048][256] 64 MB
    u16* qk     = (u16*)(ws + 167772160ull);   // [16384][128] 4 MB
    u16* WhT    = (u16*)(ws + 171966464ull);   // [4096][1024] 8 MB (dead after gemm_hv)
    u16* klT    = (u16*)(ws + 171966464ull);   // aliases WhT: [64][128][256] 4 MB (written by gemm_qk, after gemm_hv)
    u16* WoutT  = (u16*)(ws + 180355072ull);   // [1024][2048] 4 MB
    u16* Sbuf   = (u16*)(ws + 184549376ull);   // [64][256][384] 12,582,912 B
    u16* WqkT   = (u16*)(ws + 184549376ull);   // aliases Sbuf head: [128][1024] 256 KB (dead before scores)
    // total = 197,132,288 B (~188 MiB)

    convT_all<<<6272, 256, 0, stream>>>(Wh, Wout, Wqk, WhT, WoutT, WqkT);
    ln_kernel<<<16384, 256, 0, stream>>>(x, ln_w, ln_b, normed);
    gemm_hv256<<<1024, 512, 0, stream>>>(normed, WhT, bh, vT, gate);
    gemm_qk<<<dim3(1, 128), 256, 0, stream>>>(normed, WqkT, bqk, qk_w, qk_b, qk, klT);
    scores_kernel<<<128, 256, 0, stream>>>(qk, qk_w, qk_b, rel_table, Sbuf);
    kv_gemm<<<dim3(16, 64), 256, 0, stream>>>(vT, klT, kvT);
    prefix_kernel<<<4096, 256, 0, stream>>>(kvT);
    attn_gemm<<<dim3(16, 128), 256, 0, stream>>>(Sbuf, vT, kvT, gate);
    gemm_out256<<<256, 512, 0, stream>>>(gate, WoutT, bout, x, out);
}